// Round 5
// baseline (308.159 us; speedup 1.0000x reference)
//
#include <hip/hip_runtime.h>

// Bidirectional NN-MSE via MFMA.
//   loss = w * mean_n min_j ||p_n - g_j||^2 + (1-w) * mean_m min_i ||g_m - p_i||^2
//
// d^2 = qq - 2 q.r + rr computed inside mfma_f32_32x32x16_bf16 (K=16) with a
// 2-term bf16 split per operand (bf16 x bf16 products exact in fp32; absmax 0
// verified R2-R4). Refs = A (rows), queries = B (cols): each lane's 16 C-regs
// belong to one query; min over refs accumulates ELEMENTWISE (16 independent
// v_min3 chains, 0.5 min3/pair = VALU floor ~3.4 us chip-wide).
//
// R5 deltas vs R4 (nn_part was ~30 us vs ~5 us floor -> latency-bound):
//  - software prefetch of next iteration's A-frags (hide ds_read latency)
//  - 16 KB LDS (RBLK=512, SSPLIT=32): more resident blocks, smaller tail
//  - sequential-qt MFMA->min3 keeps live regs ~95 (no AGPR round-trips)
//  - memset launch dropped: nn_part block 0 zeroes out[0] (stream order
//    guarantees visibility before combine's atomicAdd)

#define NPTS   16384
#define QT     2                  // query tiles (32 cols) per wave
#define QBLK   (4 * QT * 32)      // 256 queries per block
#define QCH    (NPTS / QBLK)      // 64 query chunks
#define SSPLIT 32                 // ref splits
#define RBLK   (NPTS / SSPLIT)    // 512 refs staged per block (16 KB LDS)
#define NTILE  (RBLK / 32)        // 16 ref tiles per block
#define NB1    (2 * QCH * SSPLIT) // 4096 blocks

typedef __attribute__((ext_vector_type(8)))  __bf16 bf16x8;
typedef __attribute__((ext_vector_type(16))) float  floatx16;

union frag16 { __bf16 v[16]; uint4 q[2]; };

__device__ __forceinline__ float vmin16(floatx16 v) {
    float a = fminf(fminf(v[0], v[1]), v[2]);
    float b = fminf(fminf(v[3], v[4]), v[5]);
    float c = fminf(fminf(v[6], v[7]), v[8]);
    float d = fminf(fminf(v[9], v[10]), v[11]);
    float e = fminf(fminf(v[12], v[13]), fminf(v[14], v[15]));
    return fminf(fminf(fminf(a, b), fminf(c, d)), e);
}

__global__ __launch_bounds__(256, 4) void nn_part_kernel(
    const float* __restrict__ pred, const float* __restrict__ gt,
    float* __restrict__ partial, float* __restrict__ out)
{
    const int bx   = blockIdx.x;            // 0..NB1-1
    const int dir  = bx >> 11;              // 0: Q=pred,R=gt ; 1: Q=gt,R=pred
    const int qc   = (bx & 2047) >> 5;      // 0..63
    const int s    = bx & 31;               // 0..31
    const int tid  = threadIdx.x;
    const int lane = tid & 63;
    const int wave = tid >> 6;
    const int lid  = lane & 31;
    const int half = lane >> 5;

    if (bx == 0 && tid == 0) out[0] = 0.0f;   // replaces memset launch

    const float* __restrict__ Q = dir ? gt : pred;
    const float* __restrict__ R = dir ? pred : gt;

    __shared__ uint4 ldsA[NTILE * 64];      // [tile][half][lid], 16 KB

    // ---- stage ref A-fragments into LDS (2 refs per thread) ----
    const int rbase = s * RBLK;
    for (int j = tid; j < RBLK; j += 256) {
        const float x = R[(rbase + j) * 3 + 0];
        const float y = R[(rbase + j) * 3 + 1];
        const float z = R[(rbase + j) * 3 + 2];
        const float rr = x * x + y * y + z * z;
        const __bf16 xh = (__bf16)x, yh = (__bf16)y, zh = (__bf16)z;
        const __bf16 xl = (__bf16)(x - (float)xh);
        const __bf16 yl = (__bf16)(y - (float)yh);
        const __bf16 zl = (__bf16)(z - (float)zh);
        const __bf16 rh = (__bf16)rr;
        const __bf16 rl = (__bf16)(rr - (float)rh);
        const __bf16 one = (__bf16)1.0f;
        frag16 A;
        A.v[0]  = (__bf16)(-2.0f * (float)xh); A.v[1]  = A.v[0];
        A.v[2]  = (__bf16)(-2.0f * (float)xl); A.v[3]  = A.v[2];
        A.v[4]  = (__bf16)(-2.0f * (float)yh); A.v[5]  = A.v[4];
        A.v[6]  = (__bf16)(-2.0f * (float)yl); A.v[7]  = A.v[6];
        A.v[8]  = (__bf16)(-2.0f * (float)zh); A.v[9]  = A.v[8];
        A.v[10] = (__bf16)(-2.0f * (float)zl); A.v[11] = A.v[10];
        A.v[12] = rh;  A.v[13] = rl;  A.v[14] = one;  A.v[15] = one;
        const int tile = j >> 5, l = j & 31;
        ldsA[tile * 64 + l]      = A.q[0];   // k = 0..7
        ldsA[tile * 64 + 32 + l] = A.q[1];   // k = 8..15
    }

    // ---- query B-fragments in registers ----
    const int qbase = qc * QBLK + wave * (QT * 32);
    bf16x8 bq[QT];
#pragma unroll
    for (int qt = 0; qt < QT; ++qt) {
        const int p = qbase + qt * 32 + lid;
        const float x = Q[p * 3 + 0], y = Q[p * 3 + 1], z = Q[p * 3 + 2];
        const float qq = x * x + y * y + z * z;
        const __bf16 xh = (__bf16)x, yh = (__bf16)y, zh = (__bf16)z;
        const __bf16 xl = (__bf16)(x - (float)xh);
        const __bf16 yl = (__bf16)(y - (float)yh);
        const __bf16 zl = (__bf16)(z - (float)zh);
        const __bf16 qh = (__bf16)qq;
        const __bf16 ql = (__bf16)(qq - (float)qh);
        const __bf16 one = (__bf16)1.0f;
        frag16 B;
        B.v[0] = xh;  B.v[1]  = xl;  B.v[2]  = xh;  B.v[3]  = xl;
        B.v[4] = yh;  B.v[5]  = yl;  B.v[6]  = yh;  B.v[7]  = yl;
        B.v[8] = zh;  B.v[9]  = zl;  B.v[10] = zh;  B.v[11] = zl;
        B.v[12] = one; B.v[13] = one; B.v[14] = qh;  B.v[15] = ql;
        bq[qt] = __builtin_bit_cast(bf16x8, B.q[half]);
    }

    floatx16 zero;
#pragma unroll
    for (int k = 0; k < 16; ++k) zero[k] = 0.0f;
    floatx16 mnv[QT];
#pragma unroll
    for (int qt = 0; qt < QT; ++qt)
#pragma unroll
        for (int k = 0; k < 16; ++k) mnv[qt][k] = 3.4e38f;

    __syncthreads();

    // ---- hot loop: LDS-only, 2 ref tiles/iter, next iter prefetched ----
    const uint4* lp = ldsA + half * 32 + lid;
    uint4 c0 = lp[0];
    uint4 c1 = lp[64];
#pragma unroll
    for (int t = 0; t < NTILE / 2; ++t) {
        const bf16x8 a0 = __builtin_bit_cast(bf16x8, c0);
        const bf16x8 a1 = __builtin_bit_cast(bf16x8, c1);
        if (t + 1 < NTILE / 2) {             // prefetch next pair
            c0 = lp[(2 * t + 2) * 64];
            c1 = lp[(2 * t + 3) * 64];
        }
#pragma unroll
        for (int qt = 0; qt < QT; ++qt) {    // sequential qt: ~32 live dest regs
            floatx16 d0 = __builtin_amdgcn_mfma_f32_32x32x16_bf16(a0, bq[qt], zero, 0, 0, 0);
            floatx16 d1 = __builtin_amdgcn_mfma_f32_32x32x16_bf16(a1, bq[qt], zero, 0, 0, 0);
#pragma unroll
            for (int k = 0; k < 16; ++k)     // 16 independent v_min3 chains
                mnv[qt][k] = fminf(fminf(mnv[qt][k], d0[k]), d1[k]);
        }
    }

    // ---- tail: in-lane tree + one shuffle, plain coalesced store ----
    float* pout = partial + ((size_t)((dir * QCH + qc) * SSPLIT + s)) * QBLK
                + wave * (QT * 32);
#pragma unroll
    for (int qt = 0; qt < QT; ++qt) {
        float v = vmin16(mnv[qt]);
        v = fminf(v, __shfl_xor(v, 32));
        if (half == 0) pout[qt * 32 + lid] = v;
    }
}

// Combine: min over the SSPLIT ref-splits per query, weighted sum into out.
__global__ __launch_bounds__(256) void nn_combine_kernel(
    const float* __restrict__ partial, const float* __restrict__ weight,
    float* __restrict__ out)
{
    const int b   = blockIdx.x;        // 0..127 : dir = b>>6, qc = b&63
    const int dir = b >> 6;
    const int qc  = b & 63;
    const int t   = threadIdx.x;

    const float* p = partial + ((size_t)((dir * QCH + qc) * SSPLIT)) * QBLK;
    float v = p[t];
#pragma unroll
    for (int s = 1; s < SSPLIT; ++s)
        v = fminf(v, p[s * QBLK + t]);

    for (int off = 32; off; off >>= 1) v += __shfl_down(v, off);
    __shared__ float ws[4];
    if ((t & 63) == 0) ws[t >> 6] = v;
    __syncthreads();
    if (t == 0) {
        const float sum = ws[0] + ws[1] + ws[2] + ws[3];
        const float wgt = weight[0];
        const float scale = (dir ? (1.0f - wgt) : wgt) / (3.0f * (float)NPTS);
        atomicAdd(out, sum * scale);
    }
}

extern "C" void kernel_launch(void* const* d_in, const int* in_sizes, int n_in,
                              void* d_out, int out_size, void* d_ws, size_t ws_size,
                              hipStream_t stream) {
    const float* pred   = (const float*)d_in[0];
    const float* gt     = (const float*)d_in[1];
    const float* weight = (const float*)d_in[2];
    float* partial = (float*)d_ws;     // 2*QCH*SSPLIT*QBLK floats = 4 MB

    nn_part_kernel<<<NB1, 256, 0, stream>>>(pred, gt, partial, (float*)d_out);
    nn_combine_kernel<<<2 * QCH, 256, 0, stream>>>(partial, weight, (float*)d_out);
}

// Round 6
// 87.569 us; speedup vs baseline: 3.5190x; 3.5190x over previous
//
#include <hip/hip_runtime.h>

// Bidirectional NN-MSE via MFMA — R4 structure restored (R5's launch_bounds +
// manual prefetch caused unified-RF spills: 1.19 GB scratch traffic, 308 us).
//
//   loss = w * mean_n min_j ||p_n - g_j||^2 + (1-w) * mean_m min_i ||g_m - p_i||^2
//
// d^2 = qq - 2 q.r + rr computed inside mfma_f32_32x32x16_bf16 (K=16) with a
// 2-term bf16 split per operand (bf16 x bf16 products exact in fp32; absmax 0
// verified R2-R4). Refs = A (rows), queries = B (cols): each lane's 16 C-regs
// belong to one query; min over refs accumulates ELEMENTWISE (16 independent
// v_min3 chains), tree-reduced once per wave at the end.
//
// No device-scope atomics/fences in the hot kernel: each block plain-stores
// partial mins to a private ws slice; a tiny combine kernel min-reduces the
// 16 ref-splits and accumulates the weighted sum (128 atomicAdds total).

#define NPTS   16384
#define QT     2                  // query tiles (32 cols) per wave
#define QBLK   (4 * QT * 32)      // 256 queries per block
#define QCH    (NPTS / QBLK)      // 64 query chunks
#define SSPLIT 16                 // ref splits
#define RBLK   (NPTS / SSPLIT)    // 1024 refs staged per block (32 KB LDS)
#define NB1    (2 * QCH * SSPLIT) // 2048 blocks

typedef __attribute__((ext_vector_type(8)))  __bf16 bf16x8;
typedef __attribute__((ext_vector_type(16))) float  floatx16;

union frag16 { __bf16 v[16]; uint4 q[2]; };

__device__ __forceinline__ float vmin16(floatx16 v) {
    float a = fminf(fminf(v[0], v[1]), v[2]);
    float b = fminf(fminf(v[3], v[4]), v[5]);
    float c = fminf(fminf(v[6], v[7]), v[8]);
    float d = fminf(fminf(v[9], v[10]), v[11]);
    float e = fminf(fminf(v[12], v[13]), fminf(v[14], v[15]));
    return fminf(fminf(fminf(a, b), fminf(c, d)), e);
}

__global__ __launch_bounds__(256) void nn_part_kernel(
    const float* __restrict__ pred, const float* __restrict__ gt,
    float* __restrict__ partial, float* __restrict__ out)
{
    const int bx   = blockIdx.x;           // 0..NB1-1
    const int dir  = bx >> 10;             // 0: Q=pred,R=gt ; 1: Q=gt,R=pred
    const int qc   = (bx & 1023) >> 4;     // 0..63
    const int s    = bx & 15;              // 0..15
    const int tid  = threadIdx.x;
    const int lane = tid & 63;
    const int wave = tid >> 6;
    const int lid  = lane & 31;
    const int half = lane >> 5;

    if (bx == 0 && tid == 0) out[0] = 0.0f;   // replaces memset launch

    const float* __restrict__ Q = dir ? gt : pred;
    const float* __restrict__ R = dir ? pred : gt;

    __shared__ uint4 ldsA[RBLK * 2];       // [tile][half][lid], 32 KB

    // ---- stage ref A-fragments into LDS ----
    const int rbase = s * RBLK;
    for (int j = tid; j < RBLK; j += 256) {
        const float x = R[(rbase + j) * 3 + 0];
        const float y = R[(rbase + j) * 3 + 1];
        const float z = R[(rbase + j) * 3 + 2];
        const float rr = x * x + y * y + z * z;
        const __bf16 xh = (__bf16)x, yh = (__bf16)y, zh = (__bf16)z;
        const __bf16 xl = (__bf16)(x - (float)xh);
        const __bf16 yl = (__bf16)(y - (float)yh);
        const __bf16 zl = (__bf16)(z - (float)zh);
        const __bf16 rh = (__bf16)rr;
        const __bf16 rl = (__bf16)(rr - (float)rh);
        const __bf16 one = (__bf16)1.0f;
        frag16 A;
        A.v[0]  = (__bf16)(-2.0f * (float)xh); A.v[1]  = A.v[0];
        A.v[2]  = (__bf16)(-2.0f * (float)xl); A.v[3]  = A.v[2];
        A.v[4]  = (__bf16)(-2.0f * (float)yh); A.v[5]  = A.v[4];
        A.v[6]  = (__bf16)(-2.0f * (float)yl); A.v[7]  = A.v[6];
        A.v[8]  = (__bf16)(-2.0f * (float)zh); A.v[9]  = A.v[8];
        A.v[10] = (__bf16)(-2.0f * (float)zl); A.v[11] = A.v[10];
        A.v[12] = rh;  A.v[13] = rl;  A.v[14] = one;  A.v[15] = one;
        const int tile = j >> 5, l = j & 31;
        ldsA[tile * 64 + l]      = A.q[0];   // k = 0..7
        ldsA[tile * 64 + 32 + l] = A.q[1];   // k = 8..15
    }

    // ---- query B-fragments in registers ----
    const int qbase = qc * QBLK + wave * (QT * 32);
    bf16x8 bq[QT];
#pragma unroll
    for (int qt = 0; qt < QT; ++qt) {
        const int p = qbase + qt * 32 + lid;
        const float x = Q[p * 3 + 0], y = Q[p * 3 + 1], z = Q[p * 3 + 2];
        const float qq = x * x + y * y + z * z;
        const __bf16 xh = (__bf16)x, yh = (__bf16)y, zh = (__bf16)z;
        const __bf16 xl = (__bf16)(x - (float)xh);
        const __bf16 yl = (__bf16)(y - (float)yh);
        const __bf16 zl = (__bf16)(z - (float)zh);
        const __bf16 qh = (__bf16)qq;
        const __bf16 ql = (__bf16)(qq - (float)qh);
        const __bf16 one = (__bf16)1.0f;
        frag16 B;
        B.v[0] = xh;  B.v[1]  = xl;  B.v[2]  = xh;  B.v[3]  = xl;
        B.v[4] = yh;  B.v[5]  = yl;  B.v[6]  = yh;  B.v[7]  = yl;
        B.v[8] = zh;  B.v[9]  = zl;  B.v[10] = zh;  B.v[11] = zl;
        B.v[12] = one; B.v[13] = one; B.v[14] = qh;  B.v[15] = ql;
        bq[qt] = __builtin_bit_cast(bf16x8, B.q[half]);
    }

    floatx16 zero;
#pragma unroll
    for (int k = 0; k < 16; ++k) zero[k] = 0.0f;
    floatx16 mnv[QT];
#pragma unroll
    for (int qt = 0; qt < QT; ++qt)
#pragma unroll
        for (int k = 0; k < 16; ++k) mnv[qt][k] = 3.4e38f;

    __syncthreads();

    // ---- hot loop: LDS-only, 2 ref tiles x QT MFMAs per iteration ----
#pragma unroll 2
    for (int t = 0; t < RBLK / 32; t += 2) {
        const bf16x8 a0 = __builtin_bit_cast(bf16x8, ldsA[t * 64 + half * 32 + lid]);
        const bf16x8 a1 = __builtin_bit_cast(bf16x8, ldsA[(t + 1) * 64 + half * 32 + lid]);
#pragma unroll
        for (int qt = 0; qt < QT; ++qt) {
            floatx16 d0 = __builtin_amdgcn_mfma_f32_32x32x16_bf16(a0, bq[qt], zero, 0, 0, 0);
            floatx16 d1 = __builtin_amdgcn_mfma_f32_32x32x16_bf16(a1, bq[qt], zero, 0, 0, 0);
#pragma unroll
            for (int k = 0; k < 16; ++k)   // 16 independent v_min3 chains
                mnv[qt][k] = fminf(fminf(mnv[qt][k], d0[k]), d1[k]);
        }
    }

    // ---- tail: in-lane tree + one shuffle, plain coalesced store ----
    float* pout = partial + ((size_t)((dir * QCH + qc) * SSPLIT + s)) * QBLK
                + wave * (QT * 32);
#pragma unroll
    for (int qt = 0; qt < QT; ++qt) {
        float v = vmin16(mnv[qt]);
        v = fminf(v, __shfl_xor(v, 32));
        if (half == 0) pout[qt * 32 + lid] = v;
    }
}

// Combine: min over the SSPLIT ref-splits per query, weighted sum into out.
__global__ __launch_bounds__(256) void nn_combine_kernel(
    const float* __restrict__ partial, const float* __restrict__ weight,
    float* __restrict__ out)
{
    const int b   = blockIdx.x;        // 0..127 : dir = b>>6, qc = b&63
    const int dir = b >> 6;
    const int qc  = b & 63;
    const int t   = threadIdx.x;

    const float* p = partial + ((size_t)((dir * QCH + qc) * SSPLIT)) * QBLK;
    float v = p[t];
#pragma unroll
    for (int s = 1; s < SSPLIT; ++s)
        v = fminf(v, p[s * QBLK + t]);

    for (int off = 32; off; off >>= 1) v += __shfl_down(v, off);
    __shared__ float ws[4];
    if ((t & 63) == 0) ws[t >> 6] = v;
    __syncthreads();
    if (t == 0) {
        const float sum = ws[0] + ws[1] + ws[2] + ws[3];
        const float wgt = weight[0];
        const float scale = (dir ? (1.0f - wgt) : wgt) / (3.0f * (float)NPTS);
        atomicAdd(out, sum * scale);
    }
}

extern "C" void kernel_launch(void* const* d_in, const int* in_sizes, int n_in,
                              void* d_out, int out_size, void* d_ws, size_t ws_size,
                              hipStream_t stream) {
    const float* pred   = (const float*)d_in[0];
    const float* gt     = (const float*)d_in[1];
    const float* weight = (const float*)d_in[2];
    float* partial = (float*)d_ws;     // 2*QCH*SSPLIT*QBLK floats = 2 MB

    nn_part_kernel<<<NB1, 256, 0, stream>>>(pred, gt, partial, (float*)d_out);
    nn_combine_kernel<<<2 * QCH, 256, 0, stream>>>(partial, weight, (float*)d_out);
}